// Round 6
// baseline (1645.921 us; speedup 1.0000x reference)
//
#include <hip/hip_runtime.h>
#include <hip/hip_fp16.h>

#define N_IN_SZ   400000
#define N_OUT_SZ  200000
#define K_OFF     27
#define R_RULES   200000
#define NC        32
#define TOTAL_E   (K_OFF * R_RULES)     // 5,400,000

#define CHUNK     125                    // outputs per chunk (200000/125 = 1600 exact)
#define NCHUNK    1600
#define NBUCKET   (NCHUNK * K_OFF)       // 43,200
#define NBUCKET_PAD 44032                // 43*1024 (scan-friendly, padding stays zero)
#define N_CNT4    (NBUCKET_PAD / 4)      // 11,008
#define NSCANBLK  43

typedef unsigned int u32;
typedef unsigned long long u64;
typedef __attribute__((ext_vector_type(8))) short bf16x8;
typedef __attribute__((ext_vector_type(4))) float f32x4;

// ---------------- ws layout (bytes, all 16B-aligned) ----------------
#define SORT_OFF    0ull                           // u32[TOTAL_E] = 21,600,000
#define CNT_OFF     21600000ull
#define START_OFF   (CNT_OFF    + (u64)NBUCKET_PAD * 4)   // 21,776,128
#define CURSOR_OFF  (START_OFF  + (u64)NBUCKET_PAD * 4)   // 21,952,256
#define BSUM_OFF    (CURSOR_OFF + (u64)NBUCKET_PAD * 4)   // 22,128,384
#define BOFF_OFF    (BSUM_OFF + 256ull)
#define WS_NEW_NEEDED (BOFF_OFF + 256ull)                 // 22,128,896

// fallback (R4) ws need
#define ACC_WORDS  (N_OUT_SZ * 16)
#define WS_F16_NEEDED  ((size_t)ACC_WORDS * 4)

__device__ __forceinline__ u32 pack_bf16(float lo, float hi) {
    return (__float_as_uint(hi) & 0xFFFF0000u) | (__float_as_uint(lo) >> 16);
}

// ===========================================================================
// bucket sort pipeline: bucket = (o/125)*27 + k
// ===========================================================================
__global__ __launch_bounds__(256) void zero_cnt_kernel(uint4* __restrict__ cnt4)
{
    int i = blockIdx.x * 256 + threadIdx.x;
    if (i < N_CNT4) cnt4[i] = make_uint4(0, 0, 0, 0);
}

__global__ __launch_bounds__(256) void hist2_kernel(
    const uint4* __restrict__ oidx4, u32* __restrict__ cnt)
{
    const int i = blockIdx.x * 256 + threadIdx.x;
    const int k = blockIdx.y;
    if (i >= R_RULES / 4) return;
    uint4 o = oidx4[(size_t)k * (R_RULES / 4) + i];
    atomicAdd(&cnt[(o.x / 125u) * K_OFF + k], 1u);
    atomicAdd(&cnt[(o.y / 125u) * K_OFF + k], 1u);
    atomicAdd(&cnt[(o.z / 125u) * K_OFF + k], 1u);
    atomicAdd(&cnt[(o.w / 125u) * K_OFF + k], 1u);
}

__global__ __launch_bounds__(256) void blocksum_kernel(
    const uint4* __restrict__ cnt4, u32* __restrict__ bsum)
{
    int i4 = blockIdx.x * 256 + threadIdx.x;
    u32 s = 0;
    if (i4 < N_CNT4) {
        uint4 c = cnt4[i4];
        s = c.x + c.y + c.z + c.w;
    }
    int lane = threadIdx.x & 63;
#pragma unroll
    for (int off = 32; off > 0; off >>= 1)
        s += __shfl_down(s, off);
    __shared__ u32 ws[4];
    int wid = threadIdx.x >> 6;
    if (lane == 0) ws[wid] = s;
    __syncthreads();
    if (threadIdx.x == 0)
        bsum[blockIdx.x] = ws[0] + ws[1] + ws[2] + ws[3];
}

__global__ __launch_bounds__(256) void scanblk_kernel(
    const u32* __restrict__ bsum, u32* __restrict__ boff)
{
    __shared__ u32 lds[NSCANBLK];
    int t = threadIdx.x;
    if (t < NSCANBLK) lds[t] = bsum[t];
    __syncthreads();
    if (t == 0) {
        u32 run = 0;
        for (int i = 0; i < NSCANBLK; ++i) { u32 v = lds[i]; lds[i] = run; run += v; }
    }
    __syncthreads();
    if (t < NSCANBLK) boff[t] = lds[t];
}

__global__ __launch_bounds__(256) void scanwrite_kernel(
    const uint4* __restrict__ cnt4, const u32* __restrict__ boff,
    uint4* __restrict__ start4, uint4* __restrict__ cursor4)
{
    int i4 = blockIdx.x * 256 + threadIdx.x;
    uint4 c = (i4 < N_CNT4) ? cnt4[i4] : make_uint4(0, 0, 0, 0);
    u32 lsum = c.x + c.y + c.z + c.w;
    u32 s = lsum;
    int lane = threadIdx.x & 63;
#pragma unroll
    for (int off = 1; off < 64; off <<= 1) {
        u32 v = __shfl_up(s, off);
        if (lane >= off) s += v;
    }
    __shared__ u32 wsum[4], wbase[4];
    int wid = threadIdx.x >> 6;
    if (lane == 63) wsum[wid] = s;
    __syncthreads();
    if (threadIdx.x == 0) {
        u32 run = 0;
        for (int w = 0; w < 4; ++w) { wbase[w] = run; run += wsum[w]; }
    }
    __syncthreads();
    u32 base = boff[blockIdx.x] + wbase[wid] + (s - lsum);
    if (i4 < N_CNT4) {
        uint4 st;
        st.x = base;
        st.y = st.x + c.x;
        st.z = st.y + c.y;
        st.w = st.z + c.z;
        start4[i4]  = st;
        cursor4[i4] = st;
    }
}

__global__ __launch_bounds__(256) void fill_kernel(
    const uint4* __restrict__ iidx4, const uint4* __restrict__ oidx4,
    u32* __restrict__ cursor, u32* __restrict__ sorted)
{
    const int i = blockIdx.x * 256 + threadIdx.x;
    const int k = blockIdx.y;
    if (i >= R_RULES / 4) return;
    uint4 o  = oidx4[(size_t)k * (R_RULES / 4) + i];
    uint4 in = iidx4[(size_t)k * (R_RULES / 4) + i];
#pragma unroll
    for (int j = 0; j < 4; ++j) {
        u32 ov = (j == 0) ? o.x : (j == 1) ? o.y : (j == 2) ? o.z : o.w;
        u32 iv = (j == 0) ? in.x : (j == 1) ? in.y : (j == 2) ? in.z : in.w;
        u32 ch = ov / 125u;
        u32 ol = ov - ch * 125u;
        u32 slot = atomicAdd(&cursor[ch * K_OFF + k], 1u);
        sorted[slot] = (ol << 19) | iv;
    }
}

// ===========================================================================
// gather: block = output chunk (125 outputs). Per k-run: B = W[k] bf16 frag
// (wave-uniform), 16-entry tiles via mfma_16x16x32_bf16, C scatter-added into
// LDS f32 accumulators. No global accumulation atomics.
// ===========================================================================
__global__ __launch_bounds__(256) void gather_mfma_kernel(
    const float* __restrict__ feat,    // [N_IN, 32]
    const float* __restrict__ weight,  // [27*32, 32]
    const u32*   __restrict__ sorted,  // [TOTAL_E]
    const u32*   __restrict__ start,   // [NBUCKET+1] (padding => TOTAL_E)
    const float* __restrict__ bias,
    float*       __restrict__ out)     // [N_OUT, 32]
{
    __shared__ float acc[126 * 33];    // 125 rows + 1 trash row; stride 33 (bank spread)
    for (int t = threadIdx.x; t < 126 * 33; t += 256) acc[t] = 0.0f;
    __syncthreads();

    const int chunk = blockIdx.x;
    const int wave  = threadIdx.x >> 6;
    const int lane  = threadIdx.x & 63;
    const int row16 = lane & 15;       // A-row / C-col within fragment
    const int quad  = lane >> 4;       // k-octet selector (0..3)

    for (int k = 0; k < K_OFF; ++k) {
        const int b = chunk * K_OFF + k;
        const u32 s = start[b];
        const u32 e = start[b + 1];
        if (e <= s) continue;

        // B fragments: B[kk][col], kk = quad*8+ee, col = row16 (+16 for hi half)
        union { u32 w[4]; bf16x8 v; } bl, bh;
        const float* wk = weight + (size_t)(k * NC) * NC;
#pragma unroll
        for (int ee = 0; ee < 4; ++ee) {
            const int kk0 = quad * 8 + 2 * ee;
            float a0 = wk[(size_t)kk0 * NC + row16];
            float a1 = wk[(size_t)(kk0 + 1) * NC + row16];
            bl.w[ee] = pack_bf16(a0, a1);
            float b0 = wk[(size_t)kk0 * NC + 16 + row16];
            float b1 = wk[(size_t)(kk0 + 1) * NC + 16 + row16];
            bh.w[ee] = pack_bf16(b0, b1);
        }

        const int cnt = (int)(e - s);
        const int ntile = (cnt + 15) >> 4;
        for (int t = wave; t < ntile; t += 4) {
            const u32 base = s + ((u32)t << 4);

            // A fragment: my row's feat, k-octet = quad
            u32 ea = (base + (u32)row16 < e) ? sorted[base + row16] : (125u << 19);
            const u32 irow = ea & 0x7FFFFu;
            const float* fr = feat + (size_t)irow * NC + quad * 8;
            float4 f0 = *reinterpret_cast<const float4*>(fr);
            float4 f1 = *reinterpret_cast<const float4*>(fr + 4);
            union { u32 w[4]; bf16x8 v; } au;
            au.w[0] = pack_bf16(f0.x, f0.y);
            au.w[1] = pack_bf16(f0.z, f0.w);
            au.w[2] = pack_bf16(f1.x, f1.y);
            au.w[3] = pack_bf16(f1.z, f1.w);

            f32x4 c0 = {0.f, 0.f, 0.f, 0.f};
            f32x4 c1 = {0.f, 0.f, 0.f, 0.f};
            c0 = __builtin_amdgcn_mfma_f32_16x16x32_bf16(au.v, bl.v, c0, 0, 0, 0);
            c1 = __builtin_amdgcn_mfma_f32_16x16x32_bf16(au.v, bh.v, c1, 0, 0, 0);

            // scatter C into LDS acc: row = quad*4+rg (entry), col = row16 (channel)
#pragma unroll
            for (int rg = 0; rg < 4; ++rg) {
                const u32 ridx = base + (u32)(quad * 4 + rg);
                const u32 er = (ridx < e) ? sorted[ridx] : (125u << 19);
                const int ol = (int)(er >> 19);
                atomicAdd(&acc[ol * 33 + row16], c0[rg]);
                atomicAdd(&acc[ol * 33 + 16 + row16], c1[rg]);
            }
        }
    }
    __syncthreads();

    // out[chunk*125 + o][c] = acc[o][c] + bias[c]  (coalesced)
    for (int idx = threadIdx.x; idx < CHUNK * NC; idx += 256) {
        const int o = idx >> 5, c = idx & 31;
        out[(size_t)(chunk * CHUNK + o) * NC + c] = acc[o * 33 + c] + bias[c];
    }
}

// ===========================================================================
// Fallback paths (R4 pk-f16 atomics; R2 f32 atomics)
// ===========================================================================
__global__ __launch_bounds__(256) void zero_ws_kernel(uint4* __restrict__ ws)
{
    const int total = ACC_WORDS / 4;
    int idx = blockIdx.x * 256 + threadIdx.x;
    if (idx < total) ws[idx] = make_uint4(0, 0, 0, 0);
}

__global__ __launch_bounds__(256) void conv_scatter_f16_kernel(
    const float* __restrict__ feat, const float* __restrict__ weight,
    const int* __restrict__ in_idx, const int* __restrict__ out_idx,
    __half2* __restrict__ acc)
{
    __shared__ float2 Wlds[NC * 16];
    const int k = blockIdx.y;
    const float2* wg = reinterpret_cast<const float2*>(weight + k * NC * NC);
    for (int t = threadIdx.x; t < NC * 16; t += 256)
        Wlds[t] = wg[t];
    __syncthreads();
    const int j = threadIdx.x & 15;
    const int g = threadIdx.x >> 4;
    float2 wcol[NC];
#pragma unroll
    for (int i = 0; i < NC; ++i) wcol[i] = Wlds[i * 16 + j];
    const int rbase = blockIdx.x * 64;
    for (int rr = g; rr < 64; rr += 16) {
        const int r = rbase + rr;
        const int irow = in_idx[k * R_RULES + r];
        const int orow = out_idx[k * R_RULES + r];
        const float4* fv = reinterpret_cast<const float4*>(feat + (size_t)irow * NC);
        float a0 = 0.0f, a1 = 0.0f;
#pragma unroll
        for (int i0 = 0; i0 < 8; ++i0) {
            const float4 f = fv[i0];
            a0 += f.x * wcol[i0 * 4 + 0].x;  a1 += f.x * wcol[i0 * 4 + 0].y;
            a0 += f.y * wcol[i0 * 4 + 1].x;  a1 += f.y * wcol[i0 * 4 + 1].y;
            a0 += f.z * wcol[i0 * 4 + 2].x;  a1 += f.z * wcol[i0 * 4 + 2].y;
            a0 += f.w * wcol[i0 * 4 + 3].x;  a1 += f.w * wcol[i0 * 4 + 3].y;
        }
        unsafeAtomicAdd(acc + (size_t)orow * 16 + j, __floats2half2_rn(a0, a1));
    }
}

__global__ __launch_bounds__(256) void unpack_kernel(
    const __half2* __restrict__ acc, const float* __restrict__ bias,
    float* __restrict__ out)
{
    int t = blockIdx.x * 256 + threadIdx.x;
    if (t >= ACC_WORDS) return;
    const int j = t & 15;
    const float2 v = __half22float2(acc[t]);
    const float2 b = reinterpret_cast<const float2*>(bias)[j];
    float2 o; o.x = v.x + b.x; o.y = v.y + b.y;
    reinterpret_cast<float2*>(out)[t] = o;
}

__global__ __launch_bounds__(256) void init_out_kernel(
    const float* __restrict__ bias, float* __restrict__ out)
{
    int idx = blockIdx.x * 256 + threadIdx.x;
    const int total4 = N_OUT_SZ * NC / 4;
    if (idx >= total4) return;
    int c0 = (idx * 4) & (NC - 1);
    float4 b;
    b.x = bias[c0 + 0]; b.y = bias[c0 + 1]; b.z = bias[c0 + 2]; b.w = bias[c0 + 3];
    reinterpret_cast<float4*>(out)[idx] = b;
}

__global__ __launch_bounds__(256) void conv_scatter_kernel(
    const float* __restrict__ feat, const float* __restrict__ weight,
    const int* __restrict__ in_idx, const int* __restrict__ out_idx,
    float* __restrict__ out)
{
    __shared__ float Wlds[NC * NC];
    const int k  = blockIdx.y;
    const int c  = threadIdx.x & (NC - 1);
    const int rg = threadIdx.x >> 5;
    for (int t = threadIdx.x; t < NC * NC; t += 256)
        Wlds[t] = weight[k * NC * NC + t];
    __syncthreads();
    float wcol[NC];
#pragma unroll
    for (int i = 0; i < NC; ++i) wcol[i] = Wlds[i * NC + c];
    const int rbase = blockIdx.x * 64;
    for (int rr = rg; rr < 64; rr += 8) {
        const int r = rbase + rr;
        const int irow = in_idx[k * R_RULES + r];
        const int orow = out_idx[k * R_RULES + r];
        const float4* fv = reinterpret_cast<const float4*>(feat + (size_t)irow * NC);
        float acc = 0.0f;
#pragma unroll
        for (int i0 = 0; i0 < 8; ++i0) {
            const float4 f = fv[i0];
            acc += f.x * wcol[i0 * 4 + 0];
            acc += f.y * wcol[i0 * 4 + 1];
            acc += f.z * wcol[i0 * 4 + 2];
            acc += f.w * wcol[i0 * 4 + 3];
        }
        atomicAdd(out + (size_t)orow * NC + c, acc);
    }
}

// ---------------------------------------------------------------------------
extern "C" void kernel_launch(void* const* d_in, const int* in_sizes, int n_in,
                              void* d_out, int out_size, void* d_ws, size_t ws_size,
                              hipStream_t stream)
{
    const float* feat    = (const float*)d_in[0];
    const float* weight  = (const float*)d_in[1];
    const float* bias    = (const float*)d_in[2];
    const int*   in_idx  = (const int*)d_in[3];
    const int*   out_idx = (const int*)d_in[4];
    float*       out     = (float*)d_out;

    if (ws_size >= WS_NEW_NEEDED) {
        char* ws = (char*)d_ws;
        u32* sorted = (u32*)(ws + SORT_OFF);
        u32* cnt    = (u32*)(ws + CNT_OFF);
        u32* start  = (u32*)(ws + START_OFF);
        u32* cursor = (u32*)(ws + CURSOR_OFF);
        u32* bsum   = (u32*)(ws + BSUM_OFF);
        u32* boff   = (u32*)(ws + BOFF_OFF);

        zero_cnt_kernel<<<NSCANBLK, 256, 0, stream>>>((uint4*)cnt);
        {
            dim3 grid((R_RULES / 4 + 255) / 256, K_OFF);   // (196, 27)
            hist2_kernel<<<grid, 256, 0, stream>>>((const uint4*)out_idx, cnt);
        }
        blocksum_kernel<<<NSCANBLK, 256, 0, stream>>>((const uint4*)cnt, bsum);
        scanblk_kernel<<<1, 256, 0, stream>>>(bsum, boff);
        scanwrite_kernel<<<NSCANBLK, 256, 0, stream>>>(
            (const uint4*)cnt, boff, (uint4*)start, (uint4*)cursor);
        {
            dim3 grid((R_RULES / 4 + 255) / 256, K_OFF);
            fill_kernel<<<grid, 256, 0, stream>>>(
                (const uint4*)in_idx, (const uint4*)out_idx, cursor, sorted);
        }
        gather_mfma_kernel<<<NCHUNK, 256, 0, stream>>>(
            feat, weight, sorted, start, bias, out);
    } else if (ws_size >= WS_F16_NEEDED) {
        __half2* acc = (__half2*)d_ws;
        zero_ws_kernel<<<(ACC_WORDS / 4 + 255) / 256, 256, 0, stream>>>((uint4*)d_ws);
        dim3 grid(R_RULES / 64, K_OFF);
        conv_scatter_f16_kernel<<<grid, 256, 0, stream>>>(feat, weight, in_idx, out_idx, acc);
        unpack_kernel<<<ACC_WORDS / 256, 256, 0, stream>>>(acc, bias, out);
    } else {
        int total4 = N_OUT_SZ * NC / 4;
        init_out_kernel<<<(total4 + 255) / 256, 256, 0, stream>>>(bias, out);
        dim3 grid(R_RULES / 64, K_OFF);
        conv_scatter_kernel<<<grid, 256, 0, stream>>>(feat, weight, in_idx, out_idx, out);
    }
}

// Round 7
// 1132.918 us; speedup vs baseline: 1.4528x; 1.4528x over previous
//
#include <hip/hip_runtime.h>
#include <hip/hip_fp16.h>

#define N_IN_SZ   400000
#define N_OUT_SZ  200000
#define K_OFF     27
#define R_RULES   200000
#define NC        32
#define TOTAL_E   (K_OFF * R_RULES)     // 5,400,000

// chunk = o >> 7 (128 outputs per chunk)
#define CH_SHIFT  7
#define CH_ROWS   128
#define NCHUNK    1563                   // ceil(200000/128); last chunk has 64 rows
#define NB        (K_OFF * NCHUNK)       // 42,201 buckets, k-major: b = k*NCHUNK + ch
#define NB_PAD    43008                  // 42 * 1024
#define N_CNT4    (NB_PAD / 4)           // 10,752
#define NSCANBLK  42

#define HIST_BLK  8
#define RPH       25000                  // rules per hist/fill block (8*25000 = 200000)

typedef unsigned int u32;
typedef unsigned long long u64;

// ---------------- ws layout (bytes, 16B aligned) ----------------
#define SORT_OFF    0ull                                   // u32[TOTAL_E] = 21,600,000
#define CNT_OFF     21600000ull
#define START_OFF   (CNT_OFF   + (u64)NB_PAD * 4)          // +172,032
#define CURSOR_OFF  (START_OFF + (u64)NB_PAD * 4)
#define BSUM_OFF    (CURSOR_OFF + (u64)NB_PAD * 4)         // 22,116,096
#define BOFF_OFF    (BSUM_OFF + 256ull)
#define WS_NEW_NEEDED (BOFF_OFF + 256ull)                  // 22,116,608 (known to fit: R6 used 22,128,896)

// fallback (R4) ws need
#define ACC_WORDS  (N_OUT_SZ * 16)
#define WS_F16_NEEDED  ((size_t)ACC_WORDS * 4)

// ===========================================================================
// sort pipeline: bucket = k*NCHUNK + (o>>7). LDS-hist to avoid global atomic storms.
// ===========================================================================
__global__ __launch_bounds__(256) void zero_cnt_kernel(uint4* __restrict__ cnt4)
{
    int i = blockIdx.x * 256 + threadIdx.x;
    if (i < N_CNT4) cnt4[i] = make_uint4(0, 0, 0, 0);
}

__global__ __launch_bounds__(256) void hist_kernel(
    const int* __restrict__ out_idx, u32* __restrict__ cnt)
{
    __shared__ u32 lh[NCHUNK];
    for (int t = threadIdx.x; t < NCHUNK; t += 256) lh[t] = 0;
    __syncthreads();
    const int k    = blockIdx.y;
    const int base = blockIdx.x * RPH;
    for (int r = base + threadIdx.x; r < base + RPH; r += 256)
        atomicAdd(&lh[((u32)out_idx[(size_t)k * R_RULES + r]) >> CH_SHIFT], 1u);
    __syncthreads();
    for (int t = threadIdx.x; t < NCHUNK; t += 256) {
        u32 v = lh[t];
        if (v) atomicAdd(&cnt[(u32)k * NCHUNK + t], v);
    }
}

__global__ __launch_bounds__(256) void blocksum_kernel(
    const uint4* __restrict__ cnt4, u32* __restrict__ bsum)
{
    int i4 = blockIdx.x * 256 + threadIdx.x;
    u32 s = 0;
    if (i4 < N_CNT4) {
        uint4 c = cnt4[i4];
        s = c.x + c.y + c.z + c.w;
    }
    int lane = threadIdx.x & 63;
#pragma unroll
    for (int off = 32; off > 0; off >>= 1)
        s += __shfl_down(s, off);
    __shared__ u32 ws[4];
    int wid = threadIdx.x >> 6;
    if (lane == 0) ws[wid] = s;
    __syncthreads();
    if (threadIdx.x == 0)
        bsum[blockIdx.x] = ws[0] + ws[1] + ws[2] + ws[3];
}

__global__ __launch_bounds__(256) void scanblk_kernel(
    const u32* __restrict__ bsum, u32* __restrict__ boff)
{
    __shared__ u32 lds[NSCANBLK];
    int t = threadIdx.x;
    if (t < NSCANBLK) lds[t] = bsum[t];
    __syncthreads();
    if (t == 0) {
        u32 run = 0;
        for (int i = 0; i < NSCANBLK; ++i) { u32 v = lds[i]; lds[i] = run; run += v; }
    }
    __syncthreads();
    if (t < NSCANBLK) boff[t] = lds[t];
}

__global__ __launch_bounds__(256) void scanwrite_kernel(
    const uint4* __restrict__ cnt4, const u32* __restrict__ boff,
    uint4* __restrict__ start4, uint4* __restrict__ cursor4)
{
    int i4 = blockIdx.x * 256 + threadIdx.x;
    uint4 c = (i4 < N_CNT4) ? cnt4[i4] : make_uint4(0, 0, 0, 0);
    u32 lsum = c.x + c.y + c.z + c.w;
    u32 s = lsum;
    int lane = threadIdx.x & 63;
#pragma unroll
    for (int off = 1; off < 64; off <<= 1) {
        u32 v = __shfl_up(s, off);
        if (lane >= off) s += v;
    }
    __shared__ u32 wsum[4], wbase[4];
    int wid = threadIdx.x >> 6;
    if (lane == 63) wsum[wid] = s;
    __syncthreads();
    if (threadIdx.x == 0) {
        u32 run = 0;
        for (int w = 0; w < 4; ++w) { wbase[w] = run; run += wsum[w]; }
    }
    __syncthreads();
    u32 base = boff[blockIdx.x] + wbase[wid] + (s - lsum);
    if (i4 < N_CNT4) {
        uint4 st;
        st.x = base;
        st.y = st.x + c.x;
        st.z = st.y + c.y;
        st.w = st.z + c.z;
        start4[i4]  = st;
        cursor4[i4] = st;
    }
}

// two-phase fill: LDS hist -> reserve global base per (block,bucket) -> LDS
// running offsets -> scattered write. Global atomics: ~1600/block, not 25000.
__global__ __launch_bounds__(256) void fill_kernel(
    const int* __restrict__ in_idx, const int* __restrict__ out_idx,
    u32* __restrict__ cursor, u32* __restrict__ sorted)
{
    __shared__ u32 lh[NCHUNK];
    __shared__ u32 lbase[NCHUNK];
    const int k    = blockIdx.y;
    const int base = blockIdx.x * RPH;

    for (int t = threadIdx.x; t < NCHUNK; t += 256) lh[t] = 0;
    __syncthreads();
    for (int r = base + threadIdx.x; r < base + RPH; r += 256)
        atomicAdd(&lh[((u32)out_idx[(size_t)k * R_RULES + r]) >> CH_SHIFT], 1u);
    __syncthreads();
    for (int t = threadIdx.x; t < NCHUNK; t += 256) {
        u32 v = lh[t];
        if (v) lbase[t] = atomicAdd(&cursor[(u32)k * NCHUNK + t], v);
    }
    __syncthreads();
    for (int t = threadIdx.x; t < NCHUNK; t += 256) lh[t] = 0;
    __syncthreads();
    for (int r = base + threadIdx.x; r < base + RPH; r += 256) {
        u32 o  = (u32)out_idx[(size_t)k * R_RULES + r];
        u32 iv = (u32)in_idx[(size_t)k * R_RULES + r];
        u32 ch = o >> CH_SHIFT;
        u32 off = atomicAdd(&lh[ch], 1u);          // LDS, fast return
        sorted[lbase[ch] + off] = ((o & (u32)(CH_ROWS - 1)) << 19) | iv;
    }
}

// ===========================================================================
// gather: block = chunk (128 output rows). 16 groups x 16 lanes; group owns
// bucket (k=g, k=g+16): weight column-pair in REGISTERS (loaded once/bucket),
// entries streamed with 2-entry pipeline, ds_add_f32 into LDS accumulator.
// Zero global atomics.
// ===========================================================================
__global__ __launch_bounds__(256, 4) void gather_kernel(
    const float* __restrict__ feat,    // [N_IN, 32]
    const float* __restrict__ weight,  // [27*32, 32]
    const u32*   __restrict__ sorted,  // [TOTAL_E]
    const u32*   __restrict__ start,   // [NB_PAD] (+1 readable)
    const float* __restrict__ bias,
    float*       __restrict__ out)     // [N_OUT, 32]
{
    __shared__ float acc[CH_ROWS * 33];            // stride 33: bank spread
    for (int t = threadIdx.x; t < CH_ROWS * 33; t += 256) acc[t] = 0.0f;
    __syncthreads();

    const int chunk = blockIdx.x;
    const int j = threadIdx.x & 15;                // channel pair (2j, 2j+1)
    const int g = threadIdx.x >> 4;                // group id 0..15

    for (int k = g; k < K_OFF; k += 16) {
        const u32 s = start[(u32)k * NCHUNK + chunk];
        const u32 e = start[(u32)k * NCHUNK + chunk + 1];
        if (e <= s) continue;

        // weight column pair in regs: wcol[i] = (W[k][i][2j], W[k][i][2j+1])
        float2 wcol[NC];
        const float* wk = weight + (size_t)k * NC * NC + 2 * j;
#pragma unroll
        for (int i = 0; i < NC; ++i)
            wcol[i] = *reinterpret_cast<const float2*>(wk + (size_t)i * NC);

        u32 idx = s;
        // ---- 2-entry pipelined main loop ----
        u32 e0 = 0, e1 = 0;
        if (idx + 1 < e) { e0 = sorted[idx]; e1 = sorted[idx + 1]; }
        while (idx + 1 < e) {
            u32 n0 = 0, n1 = 0;
            if (idx + 3 < e) { n0 = sorted[idx + 2]; n1 = sorted[idx + 3]; }

            const float4* p0 = reinterpret_cast<const float4*>(feat + (size_t)(e0 & 0x7FFFFu) * NC);
            const float4* p1 = reinterpret_cast<const float4*>(feat + (size_t)(e1 & 0x7FFFFu) * NC);
            float a00 = 0.f, a01 = 0.f, a10 = 0.f, a11 = 0.f;
#pragma unroll
            for (int q = 0; q < 8; ++q) {
                float4 f0 = p0[q];
                float4 f1 = p1[q];
                a00 += f0.x * wcol[4*q+0].x; a01 += f0.x * wcol[4*q+0].y;
                a00 += f0.y * wcol[4*q+1].x; a01 += f0.y * wcol[4*q+1].y;
                a00 += f0.z * wcol[4*q+2].x; a01 += f0.z * wcol[4*q+2].y;
                a00 += f0.w * wcol[4*q+3].x; a01 += f0.w * wcol[4*q+3].y;
                a10 += f1.x * wcol[4*q+0].x; a11 += f1.x * wcol[4*q+0].y;
                a10 += f1.y * wcol[4*q+1].x; a11 += f1.y * wcol[4*q+1].y;
                a10 += f1.z * wcol[4*q+2].x; a11 += f1.z * wcol[4*q+2].y;
                a10 += f1.w * wcol[4*q+3].x; a11 += f1.w * wcol[4*q+3].y;
            }
            const int ol0 = (int)(e0 >> 19), ol1 = (int)(e1 >> 19);
            atomicAdd(&acc[ol0 * 33 + 2*j    ], a00);   // ds_add_f32, no return
            atomicAdd(&acc[ol0 * 33 + 2*j + 1], a01);
            atomicAdd(&acc[ol1 * 33 + 2*j    ], a10);
            atomicAdd(&acc[ol1 * 33 + 2*j + 1], a11);
            e0 = n0; e1 = n1;
            idx += 2;
        }
        if (idx < e) {                               // tail entry
            u32 et = sorted[idx];
            const float4* p0 = reinterpret_cast<const float4*>(feat + (size_t)(et & 0x7FFFFu) * NC);
            float a0 = 0.f, a1 = 0.f;
#pragma unroll
            for (int q = 0; q < 8; ++q) {
                float4 f0 = p0[q];
                a0 += f0.x * wcol[4*q+0].x; a1 += f0.x * wcol[4*q+0].y;
                a0 += f0.y * wcol[4*q+1].x; a1 += f0.y * wcol[4*q+1].y;
                a0 += f0.z * wcol[4*q+2].x; a1 += f0.z * wcol[4*q+2].y;
                a0 += f0.w * wcol[4*q+3].x; a1 += f0.w * wcol[4*q+3].y;
            }
            const int ol = (int)(et >> 19);
            atomicAdd(&acc[ol * 33 + 2*j    ], a0);
            atomicAdd(&acc[ol * 33 + 2*j + 1], a1);
        }
    }
    __syncthreads();

    const int obase = chunk << CH_SHIFT;
    for (int t = threadIdx.x; t < CH_ROWS * NC; t += 256) {
        const int o = obase + (t >> 5), c = t & 31;
        if (o < N_OUT_SZ)
            out[(size_t)o * NC + c] = acc[(t >> 5) * 33 + c] + bias[c];
    }
}

// ===========================================================================
// Fallback paths (R4 pk-f16 atomics; R2 f32 atomics)
// ===========================================================================
__global__ __launch_bounds__(256) void zero_ws_kernel(uint4* __restrict__ ws)
{
    const int total = ACC_WORDS / 4;
    int idx = blockIdx.x * 256 + threadIdx.x;
    if (idx < total) ws[idx] = make_uint4(0, 0, 0, 0);
}

__global__ __launch_bounds__(256) void conv_scatter_f16_kernel(
    const float* __restrict__ feat, const float* __restrict__ weight,
    const int* __restrict__ in_idx, const int* __restrict__ out_idx,
    __half2* __restrict__ acc)
{
    __shared__ float2 Wlds[NC * 16];
    const int k = blockIdx.y;
    const float2* wg = reinterpret_cast<const float2*>(weight + k * NC * NC);
    for (int t = threadIdx.x; t < NC * 16; t += 256)
        Wlds[t] = wg[t];
    __syncthreads();
    const int j = threadIdx.x & 15;
    const int g = threadIdx.x >> 4;
    float2 wcol[NC];
#pragma unroll
    for (int i = 0; i < NC; ++i) wcol[i] = Wlds[i * 16 + j];
    const int rbase = blockIdx.x * 64;
    for (int rr = g; rr < 64; rr += 16) {
        const int r = rbase + rr;
        const int irow = in_idx[(size_t)k * R_RULES + r];
        const int orow = out_idx[(size_t)k * R_RULES + r];
        const float4* fv = reinterpret_cast<const float4*>(feat + (size_t)irow * NC);
        float a0 = 0.0f, a1 = 0.0f;
#pragma unroll
        for (int i0 = 0; i0 < 8; ++i0) {
            const float4 f = fv[i0];
            a0 += f.x * wcol[i0*4+0].x;  a1 += f.x * wcol[i0*4+0].y;
            a0 += f.y * wcol[i0*4+1].x;  a1 += f.y * wcol[i0*4+1].y;
            a0 += f.z * wcol[i0*4+2].x;  a1 += f.z * wcol[i0*4+2].y;
            a0 += f.w * wcol[i0*4+3].x;  a1 += f.w * wcol[i0*4+3].y;
        }
        unsafeAtomicAdd(acc + (size_t)orow * 16 + j, __floats2half2_rn(a0, a1));
    }
}

__global__ __launch_bounds__(256) void unpack_kernel(
    const __half2* __restrict__ acc, const float* __restrict__ bias,
    float* __restrict__ out)
{
    int t = blockIdx.x * 256 + threadIdx.x;
    if (t >= ACC_WORDS) return;
    const int j = t & 15;
    const float2 v = __half22float2(acc[t]);
    const float2 b = reinterpret_cast<const float2*>(bias)[j];
    float2 o; o.x = v.x + b.x; o.y = v.y + b.y;
    reinterpret_cast<float2*>(out)[t] = o;
}

__global__ __launch_bounds__(256) void init_out_kernel(
    const float* __restrict__ bias, float* __restrict__ out)
{
    int idx = blockIdx.x * 256 + threadIdx.x;
    const int total4 = N_OUT_SZ * NC / 4;
    if (idx >= total4) return;
    int c0 = (idx * 4) & (NC - 1);
    float4 b;
    b.x = bias[c0+0]; b.y = bias[c0+1]; b.z = bias[c0+2]; b.w = bias[c0+3];
    reinterpret_cast<float4*>(out)[idx] = b;
}

__global__ __launch_bounds__(256) void conv_scatter_kernel(
    const float* __restrict__ feat, const float* __restrict__ weight,
    const int* __restrict__ in_idx, const int* __restrict__ out_idx,
    float* __restrict__ out)
{
    __shared__ float Wlds[NC * NC];
    const int k  = blockIdx.y;
    const int c  = threadIdx.x & (NC - 1);
    const int rg = threadIdx.x >> 5;
    for (int t = threadIdx.x; t < NC * NC; t += 256)
        Wlds[t] = weight[k * NC * NC + t];
    __syncthreads();
    float wcol[NC];
#pragma unroll
    for (int i = 0; i < NC; ++i) wcol[i] = Wlds[i * NC + c];
    const int rbase = blockIdx.x * 64;
    for (int rr = rg; rr < 64; rr += 8) {
        const int r = rbase + rr;
        const int irow = in_idx[(size_t)k * R_RULES + r];
        const int orow = out_idx[(size_t)k * R_RULES + r];
        const float4* fv = reinterpret_cast<const float4*>(feat + (size_t)irow * NC);
        float acc = 0.0f;
#pragma unroll
        for (int i0 = 0; i0 < 8; ++i0) {
            const float4 f = fv[i0];
            acc += f.x * wcol[i0*4+0];
            acc += f.y * wcol[i0*4+1];
            acc += f.z * wcol[i0*4+2];
            acc += f.w * wcol[i0*4+3];
        }
        atomicAdd(out + (size_t)orow * NC + c, acc);
    }
}

// ---------------------------------------------------------------------------
extern "C" void kernel_launch(void* const* d_in, const int* in_sizes, int n_in,
                              void* d_out, int out_size, void* d_ws, size_t ws_size,
                              hipStream_t stream)
{
    const float* feat    = (const float*)d_in[0];
    const float* weight  = (const float*)d_in[1];
    const float* bias    = (const float*)d_in[2];
    const int*   in_idx  = (const int*)d_in[3];
    const int*   out_idx = (const int*)d_in[4];
    float*       out     = (float*)d_out;

    if (ws_size >= WS_NEW_NEEDED) {
        char* ws = (char*)d_ws;
        u32* sorted = (u32*)(ws + SORT_OFF);
        u32* cnt    = (u32*)(ws + CNT_OFF);
        u32* start  = (u32*)(ws + START_OFF);
        u32* cursor = (u32*)(ws + CURSOR_OFF);
        u32* bsum   = (u32*)(ws + BSUM_OFF);
        u32* boff   = (u32*)(ws + BOFF_OFF);

        zero_cnt_kernel<<<NSCANBLK, 256, 0, stream>>>((uint4*)cnt);
        {
            dim3 grid(HIST_BLK, K_OFF);
            hist_kernel<<<grid, 256, 0, stream>>>(out_idx, cnt);
        }
        blocksum_kernel<<<NSCANBLK, 256, 0, stream>>>((const uint4*)cnt, bsum);
        scanblk_kernel<<<1, 256, 0, stream>>>(bsum, boff);
        scanwrite_kernel<<<NSCANBLK, 256, 0, stream>>>(
            (const uint4*)cnt, boff, (uint4*)start, (uint4*)cursor);
        {
            dim3 grid(HIST_BLK, K_OFF);
            fill_kernel<<<grid, 256, 0, stream>>>(in_idx, out_idx, cursor, sorted);
        }
        gather_kernel<<<NCHUNK, 256, 0, stream>>>(feat, weight, sorted, start, bias, out);
    } else if (ws_size >= WS_F16_NEEDED) {
        __half2* acc = (__half2*)d_ws;
        zero_ws_kernel<<<(ACC_WORDS / 4 + 255) / 256, 256, 0, stream>>>((uint4*)d_ws);
        dim3 grid(R_RULES / 64, K_OFF);
        conv_scatter_f16_kernel<<<grid, 256, 0, stream>>>(feat, weight, in_idx, out_idx, acc);
        unpack_kernel<<<ACC_WORDS / 256, 256, 0, stream>>>(acc, bias, out);
    } else {
        int total4 = N_OUT_SZ * NC / 4;
        init_out_kernel<<<(total4 + 255) / 256, 256, 0, stream>>>(bias, out);
        dim3 grid(R_RULES / 64, K_OFF);
        conv_scatter_kernel<<<grid, 256, 0, stream>>>(feat, weight, in_idx, out_idx, out);
    }
}